// Round 5
// baseline (140.241 us; speedup 1.0000x reference)
//
#include <hip/hip_runtime.h>

// Trilinear interp of [64,64,64,64] fp32 volume at 200k points.
// R11: R9's verified staged structure (async global->LDS DMA per 4^3
// bucket, gated point consumption, scalar scatter) with CHANNEL-SPLIT
// blocks: 2 blocks per bucket, each owning 8 of the 16 float4 channels.
// Tile = 125 voxels x 128B = 16 KB, 256 threads (4 waves) -> 8 blocks/CU
// resident (vs R9's 4) at full 32 waves/CU. Same total staged bytes, same
// DMA instruction count; 2x the block-level overlap to hide the per-block
// vmcnt(0) stage drain, which R9's accounting showed was ~half of gather
// time. R10 post-mortem: poison-path regression from unmasked consumption
// + vectorized scatter -> both rolled back; this round changes ONLY the
// block decomposition.

#define NBUCK   4096          // 16^3 buckets of 4^3 voxels
#define CAP     128           // mean occupancy 48.8
#define OVCAP   8192
#define HTILE_F4 1024         // 125 voxels * 8 float4 = 1000, padded to 1024
#define NGB     8192          // 2 half-blocks per bucket

typedef float __attribute__((ext_vector_type(4))) fx4;

#define GLOBAL_AS __attribute__((address_space(1)))
#define LDS_AS    __attribute__((address_space(3)))

__device__ __forceinline__ void async_copy16(const float4* g, float4* l) {
    __builtin_amdgcn_global_load_lds(
        (const GLOBAL_AS unsigned int*)(const void*)g,
        (LDS_AS unsigned int*)(void*)l, 16, 0, 0);
}

__device__ __forceinline__ float4 f4mul(float4 a, float s) {
    return make_float4(a.x * s, a.y * s, a.z * s, a.w * s);
}
__device__ __forceinline__ float4 f4fma(float4 a, float s, float4 acc) {
    return make_float4(fmaf(a.x, s, acc.x), fmaf(a.y, s, acc.y),
                       fmaf(a.z, s, acc.z), fmaf(a.w, s, acc.w));
}

__global__ __launch_bounds__(256) void scatter_kernel(
    const float* __restrict__ coords, int* __restrict__ counts,
    float4* __restrict__ buckets, float4* __restrict__ overflow, int n)
{
    int p = blockIdx.x * 256 + threadIdx.x;
    if (p >= n) return;
    float xs = coords[3 * p + 0] * 0.5f;
    float ys = coords[3 * p + 1] * 0.5f;
    float zs = coords[3 * p + 2] * 0.5f;
    int vx = (int)floorf(xs), vy = (int)floorf(ys), vz = (int)floorf(zs);
    int bucket = ((vx >> 2) << 8) | ((vy >> 2) << 4) | (vz >> 2);
    int slot = atomicAdd(&counts[bucket], 1);
    float4 v = make_float4(xs, ys, zs, __int_as_float(p));
    if (slot < CAP) {
        buckets[bucket * CAP + slot] = v;
    } else {
        int o = atomicAdd(&counts[NBUCK], 1);
        if (o < OVCAP) overflow[o] = v;
    }
}

// Pure-LDS trilinear lerp for one point over this block's 8 float4
// channels. cur holds 125 voxels x 8 float4. Two-plane evaluation keeps
// only 4 q registers live at a time.
__device__ __forceinline__ void lerp_lds_half(
    const float4* __restrict__ cur, float4 cs,
    int bx0, int by0, int bz0, int cvec, int chbase,
    float* __restrict__ out)
{
    float x = cs.x, y = cs.y, z = cs.z;
    int p = __float_as_int(cs.w);

    float fx1 = floorf(x), fx2 = fminf(ceilf(x), 63.0f);
    float fy1 = floorf(y), fy2 = fminf(ceilf(y), 63.0f);
    float fz1 = floorf(z), fz2 = fminf(ceilf(z), 63.0f);

    int ax1 = ((int)fx1 - bx0) * 25, ax2 = ((int)fx2 - bx0) * 25;
    int ay1 = ((int)fy1 - by0) * 5,  ay2 = ((int)fy2 - by0) * 5;
    int lz1 = (int)fz1 - bz0,        lz2 = (int)fz2 - bz0;

    float wx = x - fx1, wxc = fx2 - x;
    float wy = y - fy1, wyc = fy2 - y;
    float wz = z - fz1, wzc = fz2 - z;

    // z1 plane
    float4 q11 = cur[((ax1 + ay1 + lz1) << 3) + cvec];
    float4 q21 = cur[((ax2 + ay1 + lz1) << 3) + cvec];
    float4 q12 = cur[((ax1 + ay2 + lz1) << 3) + cvec];
    float4 q22 = cur[((ax2 + ay2 + lz1) << 3) + cvec];
    float4 ly1v = f4fma(f4fma(q22, wx, f4mul(q12, wxc)), wy,
                        f4mul(f4fma(q21, wx, f4mul(q11, wxc)), wyc));
    // z2 plane
    q11 = cur[((ax1 + ay1 + lz2) << 3) + cvec];
    q21 = cur[((ax2 + ay1 + lz2) << 3) + cvec];
    q12 = cur[((ax1 + ay2 + lz2) << 3) + cvec];
    q22 = cur[((ax2 + ay2 + lz2) << 3) + cvec];
    float4 ly2v = f4fma(f4fma(q22, wx, f4mul(q12, wxc)), wy,
                        f4mul(f4fma(q21, wx, f4mul(q11, wxc)), wyc));

    float4 res = f4fma(ly2v, wz, f4mul(ly1v, wzc));
    fx4 r; r.x = res.x; r.y = res.y; r.z = res.z; r.w = res.w;
    __builtin_nontemporal_store(r, (fx4*)out + (p << 4) + chbase + cvec);
}

__device__ __forceinline__ void lerp_global_store(
    const float4* __restrict__ imgv, float4 cs, int cvec,
    float* __restrict__ out)
{
    float x = cs.x, y = cs.y, z = cs.z;
    int p = __float_as_int(cs.w);

    float fx1 = floorf(x), fx2 = fminf(ceilf(x), 63.0f);
    float fy1 = floorf(y), fy2 = fminf(ceilf(y), 63.0f);
    float fz1 = floorf(z), fz2 = fminf(ceilf(z), 63.0f);

    int bx1 = ((int)fx1) << 12, bx2 = ((int)fx2) << 12;
    int by1 = ((int)fy1) << 6,  by2 = ((int)fy2) << 6;
    int iz1 = (int)fz1, iz2 = (int)fz2;

    float wx = x - fx1, wxc = fx2 - x;
    float wy = y - fy1, wyc = fy2 - y;
    float wz = z - fz1, wzc = fz2 - z;

    float4 q11 = imgv[((bx1 + by1 + iz1) << 4) + cvec];
    float4 q21 = imgv[((bx2 + by1 + iz1) << 4) + cvec];
    float4 q12 = imgv[((bx1 + by2 + iz1) << 4) + cvec];
    float4 q22 = imgv[((bx2 + by2 + iz1) << 4) + cvec];
    float4 ly1v = f4fma(f4fma(q22, wx, f4mul(q12, wxc)), wy,
                        f4mul(f4fma(q21, wx, f4mul(q11, wxc)), wyc));
    q11 = imgv[((bx1 + by1 + iz2) << 4) + cvec];
    q21 = imgv[((bx2 + by1 + iz2) << 4) + cvec];
    q12 = imgv[((bx1 + by2 + iz2) << 4) + cvec];
    q22 = imgv[((bx2 + by2 + iz2) << 4) + cvec];
    float4 ly2v = f4fma(f4fma(q22, wx, f4mul(q12, wxc)), wy,
                        f4mul(f4fma(q21, wx, f4mul(q11, wxc)), wyc));

    float4 res = f4fma(ly2v, wz, f4mul(ly1v, wzc));
    fx4 r; r.x = res.x; r.y = res.y; r.z = res.z; r.w = res.w;
    __builtin_nontemporal_store(r, (fx4*)out + (p << 4) + cvec);
}

__global__ __launch_bounds__(256, 8) void gather_kernel(
    const float* __restrict__ img, const int* __restrict__ counts,
    const float4* __restrict__ buckets, const float4* __restrict__ overflow,
    float* __restrict__ out)
{
    const float4* __restrict__ imgv = (const float4*)img;

    if (blockIdx.x < NGB) {
        __shared__ float4 tile[HTILE_F4];   // 16 KB: 125 voxels x 8 float4
        int cvec = threadIdx.x & 7;         // 0..7  (float4 channel in half)
        int grp  = threadIdx.x >> 3;        // 0..31 (point group)
        int wv   = threadIdx.x >> 6;        // wave 0..3
        int lane = threadIdx.x & 63;

        // XCD swizzle: 8 XCDs x 1024 contiguous half-blocks; both halves of
        // a bucket and z-neighbors land on the same XCD for L2 reuse.
        int seq    = (blockIdx.x & 7) * 1024 + (blockIdx.x >> 3);
        int bucket = seq >> 1;
        int half   = seq & 1;
        int chbase = half << 3;             // float4 channel base (0 or 8)
        int base   = bucket * CAP;
        int bx0 = (bucket >> 8) << 2;
        int by0 = ((bucket >> 4) & 15) << 2;
        int bz0 = (bucket & 15) << 2;

        // --- prefetch (oldest vmem first): counts + 2 points per group ---
        int cnt = counts[bucket];                  // uniform
        float4 cs0 = buckets[base + grp];          // always in-bounds (CAP=128)
        float4 cs1 = buckets[base + grp + 32];

        // --- stage 5^3 halo, this half's channels:
        //     4 waves x 4 chunks x 64 lanes x 16B = 16 KB ---
        #pragma unroll
        for (int c = 0; c < 4; c++) {
            int chunk = (wv << 2) + c;           // 0..15
            int f = chunk * 64 + lane;           // 0..1023
            int tv = min(f >> 3, 124);           // voxel 0..124 (pad clamps)
            int ch = f & 7;
            int lx = tv / 25;
            int rem = tv - lx * 25;
            int ly = rem / 5;
            int lz = rem - ly * 5;
            int gx = min(bx0 + lx, 63);
            int gy = min(by0 + ly, 63);
            int gz = min(bz0 + lz, 63);
            const float4* src =
                &imgv[(((((gx << 6) + gy) << 6) + gz) << 4) + chbase + ch];
            async_copy16(src, &tile[chunk * 64]);   // HW adds lane*16B
        }
        cnt = min(cnt, CAP);

        __syncthreads();   // vmcnt(0): all DMAs landed

        if (grp < cnt)
            lerp_lds_half(tile, cs0, bx0, by0, bz0, cvec, chbase, out);
        if (grp + 32 < cnt)
            lerp_lds_half(tile, cs1, bx0, by0, bz0, cvec, chbase, out);
        // residual (cnt > 64): ~1.4% of buckets
        for (int t = grp + 64; t < cnt; t += 32) {
            float4 cs = buckets[base + t];
            lerp_lds_half(tile, cs, bx0, by0, bz0, cvec, chbase, out);
        }
    } else {
        // overflow points (normally zero): direct global gather, full 16 ch
        int cvec = threadIdx.x & 15;
        int grp  = threadIdx.x >> 4;            // 0..15
        int ob = blockIdx.x - NGB;              // 0..31
        int cnt = min(counts[NBUCK], OVCAP);
        for (int i = (ob << 4) + grp; i < cnt; i += 32 * 16) {
            float4 cs = overflow[i];
            lerp_global_store(imgv, cs, cvec, out);
        }
    }
}

// Fallback (R1 kernel) if workspace too small.
__global__ __launch_bounds__(256) void trilerp_kernel(
    const float* __restrict__ img, const float* __restrict__ coords,
    float* __restrict__ out, int n_points)
{
    int tid = blockIdx.x * 256 + threadIdx.x;
    int p = tid >> 4;
    if (p >= n_points) return;
    int cvec = tid & 15;

    float x = coords[3 * p + 0] * 0.5f;
    float y = coords[3 * p + 1] * 0.5f;
    float z = coords[3 * p + 2] * 0.5f;

    float4 cs = make_float4(x, y, z, __int_as_float(p));
    lerp_global_store((const float4*)img, cs, cvec, out);
}

extern "C" void kernel_launch(void* const* d_in, const int* in_sizes, int n_in,
                              void* d_out, int out_size, void* d_ws, size_t ws_size,
                              hipStream_t stream) {
    const float* img    = (const float*)d_in[0];   // [1,64,64,64,64]
    const float* coords = (const float*)d_in[1];   // [1,N,3]
    float* out = (float*)d_out;                    // [1,N,64]
    int n = in_sizes[1] / 3;

    size_t counts_bytes = 32768;                              // 4097 ints, padded
    size_t buckets_off  = counts_bytes;
    size_t buckets_bytes = (size_t)NBUCK * CAP * sizeof(float4);   // 8 MB
    size_t overflow_off = buckets_off + buckets_bytes;
    size_t need = overflow_off + (size_t)OVCAP * sizeof(float4);

    if (ws_size >= need) {
        int*    counts   = (int*)d_ws;
        float4* buckets  = (float4*)((char*)d_ws + buckets_off);
        float4* overflow = (float4*)((char*)d_ws + overflow_off);

        hipMemsetAsync(counts, 0, (NBUCK + 1) * sizeof(int), stream);
        int pgrid = (n + 255) / 256;
        scatter_kernel<<<pgrid, 256, 0, stream>>>(coords, counts, buckets, overflow, n);
        gather_kernel<<<NGB + 32, 256, 0, stream>>>(img, counts, buckets, overflow, out);
    } else {
        int threads = n * 16;
        int grid = (threads + 255) / 256;
        trilerp_kernel<<<grid, 256, 0, stream>>>(img, coords, out, n);
    }
}